// Round 12
// baseline (1487.186 us; speedup 1.0000x reference)
//
#include <hip/hip_runtime.h>
#include <math.h>

#define BB  256
#define TT  2048
#define VV  64
#define DD  50
#define HH  50
#define HIDN 100
#define CHUNK  64
#define NCHUNK (TT / CHUNK)   // 32
#define RPAD   68             // ring row stride: 272B, 16B-aligned, odd 16B-chunk stride -> conflict-free
#define NCW    4              // consumer waves
#define THREADS ((1 + NCW) * 64)   // 320

// [tok][j] = seqFMA_d(embed[tok][d]*Wx[d][j]) + b_rnn[j]; cols 50..63 = 0.
__device__ float g_emWxb[VV * 64];

// ---------------------------------------------------------------------------
// XLA/Eigen fast-tanh, FMA-contracted Horner. BIT-EXACT with the reference
// trajectory (R6-R11 pass, absmax 0.015625). Do not touch: clamp
// +-7.90531110763549805, fmaf Horner, IEEE f32 divide, |x|<4e-4 passthrough.
// ---------------------------------------------------------------------------
__device__ __forceinline__ float xla_tanhf_fma(float x) {
#pragma clang fp contract(off)
  float ax = fabsf(x);
  float cx = fminf(fmaxf(x, -7.90531110763549805f), 7.90531110763549805f);
  float x2 = cx * cx;
  float p = -2.76076847742355e-16f;
  p = fmaf(x2, p, 2.00018790482477e-13f);
  p = fmaf(x2, p, -8.60467152213735e-11f);
  p = fmaf(x2, p, 5.12229709037114e-08f);
  p = fmaf(x2, p, 1.48572235717979e-05f);
  p = fmaf(x2, p, 6.37261928875436e-04f);
  p = fmaf(x2, p, 4.89352455891786e-03f);
  p = cx * p;
  float q = 1.19825839466702e-06f;
  q = fmaf(x2, q, 1.18534705686654e-04f);
  q = fmaf(x2, q, 2.26843463243900e-03f);
  q = fmaf(x2, q, 4.89352518554385e-03f);
  float r = p / q;
  return (ax < 0.0004f) ? x : r;
}

// ---------------------------------------------------------------------------
// K1: xp table, Eigen-gemm bit-emulation (unchanged from passing R6).
// ---------------------------------------------------------------------------
__global__ __launch_bounds__(256) void prep_kernel(
    const float* __restrict__ embed, const float* __restrict__ Wx,
    const float* __restrict__ b_rnn) {
#pragma clang fp contract(off)
  int o = blockIdx.x * 256 + threadIdx.x;
  if (o >= VV * 64) return;
  int v = o >> 6, j = o & 63;
  float val = 0.f;
  if (j < HH) {
    float s = 0.f;
    for (int d = 0; d < DD; ++d)
      s = fmaf(embed[v * DD + d], Wx[d * HH + j], s);
    val = s + b_rnn[j];
  }
  g_emWxb[o] = val;
}

// ---------------------------------------------------------------------------
// K2: FUSED producer-consumer, take 2.
// R7 retro-diagnosis: its 1083us was the slow READLANE producer (924us
// standalone, R8) + chunk overhead — consumers were never the bottleneck.
// Here: producer = R11's barrier-free LDS-broadcast loop (541us standalone),
// with the global hs store replaced by an LDS ring write; 4 consumer waves
// run the R9/R10 head arithmetic from the ring and write logits directly.
// hs never touches HBM (saves 134MB write + 134MB read).
// Slack: producer chunk ~40k cyc; consumer chunk ~15-20k cyc, each wave gets
// a chunk every 4 -> 8x headroom. One __syncthreads per chunk (33 total).
// Producer has NO global memory ops in-loop -> barrier drain trivial.
// All bit-critical chains unchanged (absmax must stay exactly 0.015625).
// ---------------------------------------------------------------------------
__global__ __launch_bounds__(THREADS) void fused_kernel(
    const int* __restrict__ inputs, const float* __restrict__ Wh,
    const float* __restrict__ W1, const float* __restrict__ b1,
    const float* __restrict__ W2, const float* __restrict__ b2,
    float* __restrict__ out) {
#pragma clang fp contract(off)
  const int b    = blockIdx.x;
  const int wave = threadIdx.x >> 6;
  const int lane = threadIdx.x & 63;

  __shared__ __align__(16) float emw[VV * 64];        // 16 KB
  __shared__ int toks[TT];                            // 8 KB
  __shared__ __align__(16) float hshare[64];          // broadcast buffer (fixed addr)
  __shared__ __align__(16) float ring[2][CHUNK][RPAD];// 34.8 KB, double-buffered

  for (int o = threadIdx.x; o < VV * 64; o += THREADS) emw[o] = g_emWxb[o];
  const int* rowp = inputs + (size_t)b * TT;
  for (int t = threadIdx.x; t < TT; t += THREADS) toks[t] = rowp[t];

  // producer-only state
  float whcol[HH];
  if (wave == 0) {
#pragma unroll
    for (int i = 0; i < HH; ++i)
      whcol[i] = (lane < HH) ? Wh[i * HH + lane] : 0.f;
    hshare[lane] = 0.f;   // h(-1) = 0
  }
  __syncthreads();

  float h  = 0.f;
  float xp = emw[toks[0] * 64 + lane];
  const float4* hp = reinterpret_cast<const float4*>(hshare);

  for (int it = 0; it <= NCHUNK; ++it) {
    if (wave == 0) {
      // ---------------- producer: 64 recurrence steps into ring[it&1] ----
      if (it < NCHUNK) {
        float* rb = &ring[it & 1][0][0];
        for (int s = 0; s < CHUNK; ++s) {
          const int t = it * CHUNK + s;
          // broadcast: 13 uniform ds_read_b128 of h(t-1)
          float4 hq[13];
#pragma unroll
          for (int q = 0; q < 13; ++q) hq[q] = hp[q];

          // pure FMA chain, ascending i, single accumulator (bit-exact order)
          float acc = 0.f;
#pragma unroll
          for (int q = 0; q < 12; ++q) {
            acc = fmaf(hq[q].x, whcol[4 * q + 0], acc);
            acc = fmaf(hq[q].y, whcol[4 * q + 1], acc);
            acc = fmaf(hq[q].z, whcol[4 * q + 2], acc);
            acc = fmaf(hq[q].w, whcol[4 * q + 3], acc);
          }
          acc = fmaf(hq[12].x, whcol[48], acc);
          acc = fmaf(hq[12].y, whcol[49], acc);
          float pre = xp + acc;

          // prefetch next xp (independent of h; overlaps tanh)
          int tn = toks[(t + 1 < TT) ? (t + 1) : (TT - 1)];
          float xpn = emw[tn * 64 + lane];

          h = xla_tanhf_fma(pre);
          hshare[lane] = h;            // publish for next step (same-wave RAW)
          rb[s * RPAD + lane] = h;     // publish for consumers (this chunk)
          xp = xpn;
        }
      }
    } else {
      // ---------------- consumers: head for chunk it-1 from ring ---------
      const int kc = it - 1;
      if (kc >= 0 && (kc & (NCW - 1)) == (wave - 1)) {
        const float* hrow = &ring[kc & 1][lane][0];
        float hh[52];
#pragma unroll
        for (int q = 0; q < 13; ++q) {
          float4 v = *reinterpret_cast<const float4*>(hrow + 4 * q);
          hh[4 * q + 0] = v.x;
          hh[4 * q + 1] = v.y;
          hh[4 * q + 2] = v.z;
          hh[4 * q + 3] = v.w;
        }

        float logit[VV];
#pragma unroll
        for (int jj = 0; jj < VV; ++jj) logit[jj] = b2[jj];

        for (int c = 0; c < HIDN; c += 4) {   // 25 iterations
          float a0 = 0.f, a1 = 0.f, a2 = 0.f, a3 = 0.f;
#pragma unroll
          for (int i = 0; i < HH; ++i) {      // 4 independent chains, per-chain order = R6
            const float* w1r = W1 + i * HIDN + c;
            a0 = fmaf(hh[i], w1r[0], a0);
            a1 = fmaf(hh[i], w1r[1], a1);
            a2 = fmaf(hh[i], w1r[2], a2);
            a3 = fmaf(hh[i], w1r[3], a3);
          }
          a0 += b1[c + 0]; a0 = fmaxf(a0, 0.f);
          a1 += b1[c + 1]; a1 = fmaxf(a1, 0.f);
          a2 += b1[c + 2]; a2 = fmaxf(a2, 0.f);
          a3 += b1[c + 3]; a3 = fmaxf(a3, 0.f);
          const float* v0 = W2 + (c + 0) * VV;
          const float* v1 = W2 + (c + 1) * VV;
          const float* v2 = W2 + (c + 2) * VV;
          const float* v3 = W2 + (c + 3) * VV;
#pragma unroll
          for (int jj = 0; jj < VV; ++jj) {   // ascending-c update order = R6
            float acc = logit[jj];
            acc = fmaf(a0, v0[jj], acc);
            acc = fmaf(a1, v1[jj], acc);
            acc = fmaf(a2, v2[jj], acc);
            acc = fmaf(a3, v3[jj], acc);
            logit[jj] = acc;
          }
        }

        float* orow = out + ((size_t)b * TT + (size_t)kc * CHUNK + lane) * VV;
#pragma unroll
        for (int q = 0; q < 16; ++q) {
          float4 v;
          v.x = logit[4 * q + 0];
          v.y = logit[4 * q + 1];
          v.z = logit[4 * q + 2];
          v.w = logit[4 * q + 3];
          *reinterpret_cast<float4*>(orow + 4 * q) = v;
        }
      }
    }
    __syncthreads();  // chunk it published; consumers of it-1 done -> buffer reusable
  }
}

// ---------------------------------------------------------------------------
extern "C" void kernel_launch(void* const* d_in, const int* in_sizes, int n_in,
                              void* d_out, int out_size, void* d_ws, size_t ws_size,
                              hipStream_t stream) {
  // Map inputs by element-count signature (dict order breaks the Wx/Wh tie).
  const void* p[9] = {nullptr};
  const int want[9] = {BB * TT, VV * DD, DD * HH, HH * HH, HH,
                       HH * HIDN, HIDN, HIDN * VV, VV};
  bool used[32] = {false};
  for (int k = 0; k < 9; ++k)
    for (int i = 0; i < n_in && i < 32; ++i)
      if (!used[i] && in_sizes[i] == want[k]) { p[k] = d_in[i]; used[i] = true; break; }

  const int*   inputs = (const int*)  p[0];
  const float* embed  = (const float*)p[1];
  const float* Wx     = (const float*)p[2];
  const float* Wh     = (const float*)p[3];
  const float* b_rnn  = (const float*)p[4];
  const float* W1     = (const float*)p[5];
  const float* b1     = (const float*)p[6];
  const float* W2     = (const float*)p[7];
  const float* b2     = (const float*)p[8];

  float* out = (float*)d_out;

  prep_kernel<<<(VV * 64 + 255) / 256, 256, 0, stream>>>(embed, Wx, b_rnn);
  fused_kernel<<<BB, THREADS, 0, stream>>>(inputs, Wh, W1, b1, W2, b2, out);
}

// Round 13
// 921.638 us; speedup vs baseline: 1.6136x; 1.6136x over previous
//
#include <hip/hip_runtime.h>
#include <math.h>

#define BB  256
#define TT  2048
#define VV  64
#define DD  50
#define HH  50
#define HIDN 100
#define CHUNK  64
#define NCHUNK (TT / CHUNK)   // 32
#define RPAD   65             // ring row stride (floats): bank (lane+i)%32 -> 2-way, free

// [tok][j] = seqFMA_d(embed[tok][d]*Wx[d][j]) + b_rnn[j]; cols 50..63 = 0.
__device__ float g_emWxb[VV * 64];

// ---------------------------------------------------------------------------
// XLA/Eigen fast-tanh, FMA-contracted Horner. BIT-EXACT with the reference
// trajectory (R6-R12 pass, absmax 0.015625). Do not touch: clamp
// +-7.90531110763549805, fmaf Horner, IEEE f32 divide, |x|<4e-4 passthrough.
// ---------------------------------------------------------------------------
__device__ __forceinline__ float xla_tanhf_fma(float x) {
#pragma clang fp contract(off)
  float ax = fabsf(x);
  float cx = fminf(fmaxf(x, -7.90531110763549805f), 7.90531110763549805f);
  float x2 = cx * cx;
  float p = -2.76076847742355e-16f;
  p = fmaf(x2, p, 2.00018790482477e-13f);
  p = fmaf(x2, p, -8.60467152213735e-11f);
  p = fmaf(x2, p, 5.12229709037114e-08f);
  p = fmaf(x2, p, 1.48572235717979e-05f);
  p = fmaf(x2, p, 6.37261928875436e-04f);
  p = fmaf(x2, p, 4.89352455891786e-03f);
  p = cx * p;
  float q = 1.19825839466702e-06f;
  q = fmaf(x2, q, 1.18534705686654e-04f);
  q = fmaf(x2, q, 2.26843463243900e-03f);
  q = fmaf(x2, q, 4.89352518554385e-03f);
  float r = p / q;
  return (ax < 0.0004f) ? x : r;
}

// ---------------------------------------------------------------------------
// K1: xp table, Eigen-gemm bit-emulation (unchanged from passing R6).
// ---------------------------------------------------------------------------
__global__ __launch_bounds__(256) void prep_kernel(
    const float* __restrict__ embed, const float* __restrict__ Wx,
    const float* __restrict__ b_rnn) {
#pragma clang fp contract(off)
  int o = blockIdx.x * 256 + threadIdx.x;
  if (o >= VV * 64) return;
  int v = o >> 6, j = o & 63;
  float val = 0.f;
  if (j < HH) {
    float s = 0.f;
    for (int d = 0; d < DD; ++d)
      s = fmaf(embed[v * DD + d], Wx[d * HH + j], s);
    val = s + b_rnn[j];
  }
  g_emWxb[o] = val;
}

// ---------------------------------------------------------------------------
// Consumer: head for one chunk, lane = timestep row, logit columns
// [LO, LO+NC). NC <= 24 -> hh[50]+logit[24]+temps ~ 85 VGPR, NO SPILL
// (R12's single-wave-full-row logit[64]+hh[52] spilled at VGPR=100 -> 2x
// regression). Hidden a0..a3 recomputed per wave (redundant, bit-identical).
// Per-element chains identical to R6 head: a-chain ascending i; logit
// updates ascending c; relu after +b1.
// ---------------------------------------------------------------------------
template <int LO, int NC>
__device__ __forceinline__ void consume_chunk(
    const float* hrow,   // &ring[buf][lane][0]
    const float* __restrict__ W1, const float* __restrict__ b1,
    const float* __restrict__ W2, const float* __restrict__ b2,
    float* orow) {       // &out[(b*TT + kc*CHUNK + lane)*VV]
#pragma clang fp contract(off)
  float hh[HH];
#pragma unroll
  for (int i = 0; i < HH; ++i) hh[i] = hrow[i];   // ds_read_b32, (lane+i)%32 -> 2-way free

  float logit[NC];
#pragma unroll
  for (int jj = 0; jj < NC; ++jj) logit[jj] = b2[LO + jj];

  for (int c = 0; c < HIDN; c += 4) {   // 25 iterations
    float a0 = 0.f, a1 = 0.f, a2 = 0.f, a3 = 0.f;
#pragma unroll
    for (int i = 0; i < HH; ++i) {      // 4 independent chains, per-chain order = R6
      const float* w1r = W1 + i * HIDN + c;
      a0 = fmaf(hh[i], w1r[0], a0);
      a1 = fmaf(hh[i], w1r[1], a1);
      a2 = fmaf(hh[i], w1r[2], a2);
      a3 = fmaf(hh[i], w1r[3], a3);
    }
    a0 += b1[c + 0]; a0 = fmaxf(a0, 0.f);
    a1 += b1[c + 1]; a1 = fmaxf(a1, 0.f);
    a2 += b1[c + 2]; a2 = fmaxf(a2, 0.f);
    a3 += b1[c + 3]; a3 = fmaxf(a3, 0.f);
    const float* v0 = W2 + (c + 0) * VV + LO;
    const float* v1 = W2 + (c + 1) * VV + LO;
    const float* v2 = W2 + (c + 2) * VV + LO;
    const float* v3 = W2 + (c + 3) * VV + LO;
#pragma unroll
    for (int jj = 0; jj < NC; ++jj) {   // ascending-c update order = R6
      float acc = logit[jj];
      acc = fmaf(a0, v0[jj], acc);
      acc = fmaf(a1, v1[jj], acc);
      acc = fmaf(a2, v2[jj], acc);
      acc = fmaf(a3, v3[jj], acc);
      logit[jj] = acc;
    }
  }

#pragma unroll
  for (int q = 0; q < NC / 4; ++q) {   // LO in {0,24,44}: 0/96/176B, 16B-aligned
    float4 v;
    v.x = logit[4 * q + 0];
    v.y = logit[4 * q + 1];
    v.z = logit[4 * q + 2];
    v.w = logit[4 * q + 3];
    *reinterpret_cast<float4*>(orow + LO + 4 * q) = v;
  }
}

// ---------------------------------------------------------------------------
// K2: FUSED producer-consumer, take 3.
// R12 failure: 1 consumer wave owned a whole chunk (logit[64] -> spill at
// VGPR=100 -> consumer >> producer window -> barrier gated). Fix = R7's
// register-sized column split: 3 consumer waves x {24,20,20} cols, ALL waves
// work EVERY chunk. 4 waves total -> one per SIMD (no producer SIMD-share).
// Producer = R11's 541us barrier-free LDS-broadcast loop; global hs store
// DELETED (ring only) -> 268MB HBM round-trip gone.
// Consumer/chunk ~15k cyc << producer ~40k -> producer-bound.
// All bit-critical chains unchanged (absmax must stay exactly 0.015625).
// ---------------------------------------------------------------------------
__global__ __launch_bounds__(256) void fused_kernel(
    const int* __restrict__ inputs, const float* __restrict__ Wh,
    const float* __restrict__ W1, const float* __restrict__ b1,
    const float* __restrict__ W2, const float* __restrict__ b2,
    float* __restrict__ out) {
#pragma clang fp contract(off)
  const int b    = blockIdx.x;
  const int wave = threadIdx.x >> 6;
  const int lane = threadIdx.x & 63;

  __shared__ __align__(16) float emw[VV * 64];          // 16 KB
  __shared__ int toks[TT];                              // 8 KB
  __shared__ __align__(16) float hshare[64];            // broadcast buffer
  __shared__ __align__(16) float ring[2][CHUNK][RPAD];  // 33.3 KB

  for (int o = threadIdx.x; o < VV * 64; o += 256) emw[o] = g_emWxb[o];
  const int* rowp = inputs + (size_t)b * TT;
  for (int t = threadIdx.x; t < TT; t += 256) toks[t] = rowp[t];

  float whcol[HH];
  if (wave == 0) {
#pragma unroll
    for (int i = 0; i < HH; ++i)
      whcol[i] = (lane < HH) ? Wh[i * HH + lane] : 0.f;
    hshare[lane] = 0.f;   // h(-1) = 0
  }
  __syncthreads();

  float h  = 0.f;
  float xp = emw[toks[0] * 64 + lane];
  const float4* hp = reinterpret_cast<const float4*>(hshare);

  for (int it = 0; it <= NCHUNK; ++it) {
    if (wave == 0) {
      // ---------------- producer: 64 recurrence steps into ring[it&1] ----
      if (it < NCHUNK) {
        float* rb = &ring[it & 1][0][0];
        for (int s = 0; s < CHUNK; ++s) {
          const int t = it * CHUNK + s;
          // broadcast: 13 uniform ds_read_b128 of h(t-1)
          float4 hq[13];
#pragma unroll
          for (int q = 0; q < 13; ++q) hq[q] = hp[q];

          // pure FMA chain, ascending i, single accumulator (bit-exact order)
          float acc = 0.f;
#pragma unroll
          for (int q = 0; q < 12; ++q) {
            acc = fmaf(hq[q].x, whcol[4 * q + 0], acc);
            acc = fmaf(hq[q].y, whcol[4 * q + 1], acc);
            acc = fmaf(hq[q].z, whcol[4 * q + 2], acc);
            acc = fmaf(hq[q].w, whcol[4 * q + 3], acc);
          }
          acc = fmaf(hq[12].x, whcol[48], acc);
          acc = fmaf(hq[12].y, whcol[49], acc);
          float pre = xp + acc;

          // prefetch next xp (independent of h; overlaps tanh)
          int tn = toks[(t + 1 < TT) ? (t + 1) : (TT - 1)];
          float xpn = emw[tn * 64 + lane];

          h = xla_tanhf_fma(pre);
          hshare[lane] = h;            // publish for next step (same-wave RAW)
          rb[s * RPAD + lane] = h;     // publish for consumers; (s+lane)%32 -> 2-way free
          xp = xpn;
        }
      }
    } else {
      // ---------------- consumers: head for chunk it-1 (all 3 waves) -----
      const int kc = it - 1;
      if (kc >= 0) {
        const float* hrow = &ring[kc & 1][lane][0];
        float* orow = out + ((size_t)b * TT + (size_t)kc * CHUNK + lane) * VV;
        if (wave == 1)      consume_chunk<0, 24>(hrow, W1, b1, W2, b2, orow);
        else if (wave == 2) consume_chunk<24, 20>(hrow, W1, b1, W2, b2, orow);
        else                consume_chunk<44, 20>(hrow, W1, b1, W2, b2, orow);
      }
    }
    __syncthreads();  // chunk it published; consumers of it-1 done -> buffer reusable
  }
}

// ---------------------------------------------------------------------------
extern "C" void kernel_launch(void* const* d_in, const int* in_sizes, int n_in,
                              void* d_out, int out_size, void* d_ws, size_t ws_size,
                              hipStream_t stream) {
  // Map inputs by element-count signature (dict order breaks the Wx/Wh tie).
  const void* p[9] = {nullptr};
  const int want[9] = {BB * TT, VV * DD, DD * HH, HH * HH, HH,
                       HH * HIDN, HIDN, HIDN * VV, VV};
  bool used[32] = {false};
  for (int k = 0; k < 9; ++k)
    for (int i = 0; i < n_in && i < 32; ++i)
      if (!used[i] && in_sizes[i] == want[k]) { p[k] = d_in[i]; used[i] = true; break; }

  const int*   inputs = (const int*)  p[0];
  const float* embed  = (const float*)p[1];
  const float* Wx     = (const float*)p[2];
  const float* Wh     = (const float*)p[3];
  const float* b_rnn  = (const float*)p[4];
  const float* W1     = (const float*)p[5];
  const float* b1     = (const float*)p[6];
  const float* W2     = (const float*)p[7];
  const float* b2     = (const float*)p[8];

  float* out = (float*)d_out;

  prep_kernel<<<(VV * 64 + 255) / 256, 256, 0, stream>>>(embed, Wx, b_rnn);
  fused_kernel<<<BB, 256, 0, stream>>>(inputs, Wh, W1, b1, W2, b2, out);
}

// Round 14
// 729.091 us; speedup vs baseline: 2.0398x; 1.2641x over previous
//
#include <hip/hip_runtime.h>
#include <math.h>

#define BB  256
#define TT  2048
#define VV  64
#define DD  50
#define HH  50
#define HIDN 100

// [tok][j] = seqFMA_d(embed[tok][d]*Wx[d][j]) + b_rnn[j]; cols 50..63 = 0.
__device__ float g_emWxb[VV * 64];
// [c][i] = W1[i][c], i 50..63 = 0. Contiguous 256B per c -> 4 K$ lines, wide s_loads.
__device__ float g_W1T[HIDN * 64];

// ---------------------------------------------------------------------------
// XLA/Eigen fast-tanh, FMA-contracted Horner. BIT-EXACT with the reference
// trajectory (R6-R13 pass, absmax 0.015625). Do not touch: clamp
// +-7.90531110763549805, fmaf Horner, IEEE f32 divide, |x|<4e-4 passthrough.
// ---------------------------------------------------------------------------
__device__ __forceinline__ float xla_tanhf_fma(float x) {
#pragma clang fp contract(off)
  float ax = fabsf(x);
  float cx = fminf(fmaxf(x, -7.90531110763549805f), 7.90531110763549805f);
  float x2 = cx * cx;
  float p = -2.76076847742355e-16f;
  p = fmaf(x2, p, 2.00018790482477e-13f);
  p = fmaf(x2, p, -8.60467152213735e-11f);
  p = fmaf(x2, p, 5.12229709037114e-08f);
  p = fmaf(x2, p, 1.48572235717979e-05f);
  p = fmaf(x2, p, 6.37261928875436e-04f);
  p = fmaf(x2, p, 4.89352455891786e-03f);
  p = cx * p;
  float q = 1.19825839466702e-06f;
  q = fmaf(x2, q, 1.18534705686654e-04f);
  q = fmaf(x2, q, 2.26843463243900e-03f);
  q = fmaf(x2, q, 4.89352518554385e-03f);
  float r = p / q;
  return (ax < 0.0004f) ? x : r;
}

// ---------------------------------------------------------------------------
// K1: xp table, Eigen-gemm bit-emulation (unchanged from passing R6).
// ---------------------------------------------------------------------------
__global__ __launch_bounds__(256) void prep_kernel(
    const float* __restrict__ embed, const float* __restrict__ Wx,
    const float* __restrict__ b_rnn) {
#pragma clang fp contract(off)
  int o = blockIdx.x * 256 + threadIdx.x;
  if (o >= VV * 64) return;
  int v = o >> 6, j = o & 63;
  float val = 0.f;
  if (j < HH) {
    float s = 0.f;
    for (int d = 0; d < DD; ++d)
      s = fmaf(embed[v * DD + d], Wx[d * HH + j], s);
    val = s + b_rnn[j];
  }
  g_emWxb[o] = val;
}

// K1b: W1 transpose (pure data movement, bit-exact trivially).
__global__ __launch_bounds__(256) void prep2_kernel(const float* __restrict__ W1) {
  int o = blockIdx.x * 256 + threadIdx.x;
  if (o >= HIDN * 64) return;
  int c = o >> 6, i = o & 63;
  g_W1T[o] = (i < HH) ? W1[i * HIDN + c] : 0.f;
}

// ---------------------------------------------------------------------------
// K2: recurrence, PIPELINED LDS broadcast.
// R11 (541us, 634cyc/step) decomposition: source loaded all 13 hq b128s
// before any FMA -> coarse lgkm wait -> chain starts after LAST read
// (~write+276), +200 chain +80 tanh = 634. Fix: stagger reads vs chain
// (4 ahead, consume-one/load-one) so compiler emits fine lgkmcnt(N) and
// FMA0 starts at ~write+130. Loads reordered ONLY — the 50-FMA single-acc
// ascending chain, xp add, tanh are bit-identical (chaos gain ~1.3e7: any
// arithmetic reorder => fail; load order is not arithmetic).
// Lanes >= 50: whcol=0, xp=0 -> h=0 -> hs cols 50..63 = 0.
// ---------------------------------------------------------------------------
__global__ __launch_bounds__(64) void rnn_kernel(
    const int* __restrict__ inputs, const float* __restrict__ Wh,
    float* hs) {
#pragma clang fp contract(off)
  const int b = blockIdx.x;
  const int lane = threadIdx.x;

  __shared__ __align__(16) float emw[VV * 64];  // 16 KB
  __shared__ int toks[TT];                      // 8 KB
  __shared__ __align__(16) float hshare[64];

  for (int o = lane; o < VV * 64; o += 64) emw[o] = g_emWxb[o];
  const int* rowp = inputs + (size_t)b * TT;
  for (int t = lane; t < TT; t += 64) toks[t] = rowp[t];

  float whcol[HH];
#pragma unroll
  for (int i = 0; i < HH; ++i)
    whcol[i] = (lane < HH) ? Wh[i * HH + lane] : 0.f;

  hshare[lane] = 0.f;   // h(-1) = 0
  __syncthreads();      // once (staging)

  float* outp = hs + (size_t)b * TT * 64;
  float h = 0.f;
  float xp = emw[toks[0] * 64 + lane];
  const float4* hp = reinterpret_cast<const float4*>(hshare);

#define FMA4(v, base)                         \
  acc = fmaf((v).x, whcol[(base) + 0], acc);  \
  acc = fmaf((v).y, whcol[(base) + 1], acc);  \
  acc = fmaf((v).z, whcol[(base) + 2], acc);  \
  acc = fmaf((v).w, whcol[(base) + 3], acc);

  for (int t = 0; t < TT; ++t) {
    // staggered broadcast: 4 reads ahead, then consume-one/load-one
    float4 h0 = hp[0];
    float4 h1 = hp[1];
    float4 h2 = hp[2];
    float4 h3 = hp[3];
    float acc = 0.f;
    FMA4(h0, 0)  float4 h4 = hp[4];
    FMA4(h1, 4)  float4 h5 = hp[5];
    FMA4(h2, 8)  float4 h6 = hp[6];
    FMA4(h3, 12) float4 h7 = hp[7];
    FMA4(h4, 16) float4 h8 = hp[8];
    FMA4(h5, 20) float4 h9 = hp[9];
    FMA4(h6, 24) float4 h10 = hp[10];
    FMA4(h7, 28) float4 h11 = hp[11];
    FMA4(h8, 32) float4 h12 = hp[12];
    FMA4(h9, 36)
    FMA4(h10, 40)
    FMA4(h11, 44)
    acc = fmaf(h12.x, whcol[48], acc);
    acc = fmaf(h12.y, whcol[49], acc);
    float pre = xp + acc;

    // prefetch next xp (independent of h; overlaps tanh)
    int tn = toks[(t + 1 < TT) ? (t + 1) : (TT - 1)];
    float xpn = emw[tn * 64 + lane];

    h = xla_tanhf_fma(pre);
    hshare[lane] = h;                  // publish early (same-wave RAW, no barrier)
    outp[(size_t)t * 64 + lane] = h;   // coalesced fire-and-forget (never drained)
    xp = xpn;
  }
#undef FMA4
}

// ---------------------------------------------------------------------------
// K3: MLP head with W1T. One THREAD per (b,t) row, 4-way c-unroll. The
// a-chains read W1T[c][i] == W1[i][c] (same bits) ascending i -> per-element
// chains bit-identical to R6 (absmax must stay exactly 0.015625). W1T rows
// contiguous (256B) -> 4 K$ lines/c-group (was ~50 with stride-400B W1).
// hs/out may alias -> NO restrict; thread r reads row r before writing it.
// ---------------------------------------------------------------------------
__global__ __launch_bounds__(256) void head_kernel(
    const float* hs, const float* __restrict__ b1,
    const float* __restrict__ W2, const float* __restrict__ b2,
    float* out) {
#pragma clang fp contract(off)
  const int r = blockIdx.x * 256 + threadIdx.x;  // 0 .. B*T-1
  const float* hrow = hs + (size_t)r * 64;

  float h[52];
#pragma unroll
  for (int q = 0; q < 13; ++q) {     // hrow is 256B-aligned
    float4 v = *reinterpret_cast<const float4*>(hrow + 4 * q);
    h[4 * q + 0] = v.x;
    h[4 * q + 1] = v.y;
    h[4 * q + 2] = v.z;
    h[4 * q + 3] = v.w;
  }

  float logit[VV];
#pragma unroll
  for (int jj = 0; jj < VV; ++jj) logit[jj] = b2[jj];

  for (int c = 0; c < HIDN; c += 4) {   // 25 iterations
    const float* w0 = g_W1T + (c + 0) * 64;
    const float* w1 = g_W1T + (c + 1) * 64;
    const float* w2c = g_W1T + (c + 2) * 64;
    const float* w3 = g_W1T + (c + 3) * 64;
    float a0 = 0.f, a1 = 0.f, a2 = 0.f, a3 = 0.f;
#pragma unroll
    for (int i = 0; i < HH; ++i) {      // 4 independent chains, per-chain order = R6
      a0 = fmaf(h[i], w0[i], a0);
      a1 = fmaf(h[i], w1[i], a1);
      a2 = fmaf(h[i], w2c[i], a2);
      a3 = fmaf(h[i], w3[i], a3);
    }
    a0 += b1[c + 0]; a0 = fmaxf(a0, 0.f);
    a1 += b1[c + 1]; a1 = fmaxf(a1, 0.f);
    a2 += b1[c + 2]; a2 = fmaxf(a2, 0.f);
    a3 += b1[c + 3]; a3 = fmaxf(a3, 0.f);
    const float* v0 = W2 + (c + 0) * VV;
    const float* v1 = W2 + (c + 1) * VV;
    const float* v2 = W2 + (c + 2) * VV;
    const float* v3 = W2 + (c + 3) * VV;
#pragma unroll
    for (int jj = 0; jj < VV; ++jj) {   // ascending-c update order = R6
      float acc = logit[jj];
      acc = fmaf(a0, v0[jj], acc);
      acc = fmaf(a1, v1[jj], acc);
      acc = fmaf(a2, v2[jj], acc);
      acc = fmaf(a3, v3[jj], acc);
      logit[jj] = acc;
    }
  }

  float* orow = out + (size_t)r * 64;
#pragma unroll
  for (int q = 0; q < 16; ++q) {
    float4 v;
    v.x = logit[4 * q + 0];
    v.y = logit[4 * q + 1];
    v.z = logit[4 * q + 2];
    v.w = logit[4 * q + 3];
    *reinterpret_cast<float4*>(orow + 4 * q) = v;
  }
}

// ---------------------------------------------------------------------------
extern "C" void kernel_launch(void* const* d_in, const int* in_sizes, int n_in,
                              void* d_out, int out_size, void* d_ws, size_t ws_size,
                              hipStream_t stream) {
  // Map inputs by element-count signature (dict order breaks the Wx/Wh tie).
  const void* p[9] = {nullptr};
  const int want[9] = {BB * TT, VV * DD, DD * HH, HH * HH, HH,
                       HH * HIDN, HIDN, HIDN * VV, VV};
  bool used[32] = {false};
  for (int k = 0; k < 9; ++k)
    for (int i = 0; i < n_in && i < 32; ++i)
      if (!used[i] && in_sizes[i] == want[k]) { p[k] = d_in[i]; used[i] = true; break; }

  const int*   inputs = (const int*)  p[0];
  const float* embed  = (const float*)p[1];
  const float* Wx     = (const float*)p[2];
  const float* Wh     = (const float*)p[3];
  const float* b_rnn  = (const float*)p[4];
  const float* W1     = (const float*)p[5];
  const float* b1     = (const float*)p[6];
  const float* W2     = (const float*)p[7];
  const float* b2     = (const float*)p[8];

  float* out = (float*)d_out;
  float* hs = (ws_size >= (size_t)(BB * TT * 64) * sizeof(float))
                  ? (float*)d_ws : out;

  prep_kernel<<<(VV * 64 + 255) / 256, 256, 0, stream>>>(embed, Wx, b_rnn);
  prep2_kernel<<<(HIDN * 64 + 255) / 256, 256, 0, stream>>>(W1);
  rnn_kernel<<<BB, 64, 0, stream>>>(inputs, Wh, hs);
  head_kernel<<<(BB * TT) / 256, 256, 0, stream>>>(hs, b1, W2, b2, out);
}